// Round 10
// baseline (136.180 us; speedup 1.0000x reference)
//
#include <hip/hip_runtime.h>

// Fourier-shift patch reassembly = two circulant matmuls + rank-1 term, on MFMA.
//   U[r,x] = sum_m P~[r,m] px[x-m+96] ;  V[y,x] = sum_r U[r,x] py[y-r+96]
//   out[b,y,x] = sum_c (-1)^{x+y} ( V - sx sy Qt ) / M^2
// Split-bf16 (x = hi+lo): hi*hi + hi*lo + lo*hi ~ fp32.
// ROUND-10 CHANGE (one structural change): software-pipelined channel loop.
//   Phase X(c): [stage-B(c-1): sU + py-REGS only] ∥ [table build(c) + Q(c)] -> bar
//   Phase Y(c): [A-frags from prefetched regs; stage-A per-tx -> sU; hoist py->regs] -> bar
//   2 barriers/channel (was 3), transcendental VALU hidden under stage-B MFMAs.
// CG=2, WPB=8, 1024 WGs (4 WG/CU work, 3 resident: LDS 44.5KB, lb(256,3)).
// Prefetch: channel-PAIR f32x2 (16B-line-friendly, round-9-proven FETCH ~20MB).

#define NCH 16
#define CG  2
#define WPB 8

typedef __attribute__((ext_vector_type(8))) short bf16x8;
typedef __attribute__((ext_vector_type(4))) float f32x4;
typedef __attribute__((ext_vector_type(2))) float f32x2;
typedef __attribute__((ext_vector_type(2))) uint uint2v;

__device__ __forceinline__ ushort f2bf(float x) {
    union { float f; uint u; } v; v.f = x;
    uint r = v.u + 0x7fffu + ((v.u >> 16) & 1u);
    return (ushort)(r >> 16);
}
__device__ __forceinline__ float bf2f(ushort h) {
    union { uint u; float f; } v; v.u = ((uint)h) << 16; return v.f;
}
__device__ __forceinline__ int uSw(int x) { return (x ^ (x >> 3)) & 7; }

// sin(pi*d) with range reduction; sign folded for odd integer part
__device__ __forceinline__ void sinpi_pair(float dy, float dx, float& sy, float& sx) {
    const float PI = 3.14159265358979323846f;
    float kdxf = rintf(dx), kdyf = rintf(dy);
    sx = sinf((dx - kdxf) * PI); if (((int)kdxf) & 1) sx = -sx;
    sy = sinf((dy - kdyf) * PI); if (((int)kdyf) & 1) sy = -sy;
}

// reversed duplicated split tables: R[j] = table[223-j], 8 alignment copies
__device__ __forceinline__ void build_tables(ushort (*sTab)[2][8][200],
                                             float dx, float dy, float sx, float sy,
                                             int tid) {
    const float PI = 3.14159265358979323846f;
    for (int job = tid; job < 384; job += 256) {
        const int tbl = (job >= 192) ? 1 : 0;
        const int j   = job - 192 * tbl;
        const float d  = tbl ? dy : dx;
        const float sd = tbl ? sy : sx;
        const int t = 223 - j;
        float u   = (float)t - d;
        float ur  = u - 128.f * rintf(u * (1.f / 128.f));
        float th  = ur * (PI / 128.f);
        float sth = sinf(th), cth = cosf(th);
        float v = (fabsf(sth) < 1e-12f) ? ((t & 1) ? 128.f : -128.f)
                                        : sd * cth / sth;
        const ushort hi = f2bf(v);
        const ushort lo = f2bf(v - bf2f(hi));
        #pragma unroll
        for (int a = 0; a < 8; ++a) {
            sTab[tbl][0][a][j + a] = hi;
            sTab[tbl][1][a][j + a] = lo;
        }
    }
}

template<bool USE_WS>
__global__ __launch_bounds__(256, 3)
void reassemble_mfma(const float* __restrict__ patches,
                     const float* __restrict__ positions,
                     float* __restrict__ dst, int B)
{
    __shared__ __align__(16) ushort sTab[2][2][8][200]; // [x/y][hi/lo][copy][slot] 12.8KB
    __shared__ __align__(16) ushort sU[2][8192];        // [hi/lo] U^T swizzled     32KB
    __shared__ float sQ[4];

    const int tid  = threadIdx.x;
    const int lane = tid & 63;
    const int wv   = tid >> 6;    // wave 0..3
    const int nn   = lane & 15;   // frag row/col
    const int hh   = lane >> 4;   // frag k-group 0..3

    int b, cg;
    if (B == 128) {  // XCD map: all 8 WGs of an image on one XCD's L2
        const int xcd = blockIdx.x & 7, slot = blockIdx.x >> 3;
        b = xcd * 16 + (slot >> 3); cg = slot & 7;
    } else { b = blockIdx.x >> 3; cg = blockIdx.x & 7; }

    const f32x4 zero = {0.f, 0.f, 0.f, 0.f};
    f32x4 acc[2][8];                      // stage-B: ty in {2wv,2wv+1} x 8 tx
    #pragma unroll
    for (int i = 0; i < 2; ++i)
        #pragma unroll
        for (int j = 0; j < 8; ++j) acc[i][j] = zero;
    float Stot = 0.f;

    const int r = 16 * wv + nn;           // this lane's patch row (stage A)

    // ---- one-time prefetch: this WG's channel PAIR, 16 x f32x2 per lane ----
    f32x2 raw[2][8];
    {
        const float* srcq = patches + (size_t)b * 65536 + CG * cg;
        #pragma unroll
        for (int ks = 0; ks < 2; ++ks)
            #pragma unroll
            for (int d8 = 0; d8 < 8; ++d8) {
                const int m = 32 * ks + 8 * hh + d8;
                raw[ks][d8] = *(const f32x2*)&srcq[(size_t)(r * 64 + m) * 16];
            }
    }

    // ---- phase X(0): tables(c0) + Q(c0); no stage-B yet ----
    {
        const int c0 = cg * CG;
        const float dy = positions[(b * NCH + c0) * 2 + 0];
        const float dx = positions[(b * NCH + c0) * 2 + 1];
        float sx, sy; sinpi_pair(dy, dx, sy, sx);
        build_tables(sTab, dx, dy, sx, sy, tid);
        float qp = 0.f;
        #pragma unroll
        for (int ks = 0; ks < 2; ++ks)
            #pragma unroll
            for (int d8 = 0; d8 < 8; ++d8) {
                const int m = 32 * ks + 8 * hh + d8;
                const float v = raw[ks][d8][0];
                qp += ((r + m) & 1) ? -v : v;
            }
        #pragma unroll
        for (int off = 32; off >= 1; off >>= 1) qp += __shfl_down(qp, off, 64);
        if (lane == 0) sQ[wv] = qp;
    }
    __syncthreads();   // tables(c0) + sQ(c0) ready

    bf16x8 P0h[2], P0l[2], P1h[2], P1l[2];   // stage-B A-operands, hoisted to regs

    #pragma unroll
    for (int cc = 0; cc < CG; ++cc) {     // MUST unroll: raw[..][..][cc]
        const int c = cg * CG + cc;

        // ===== phase Y(cc): A-frags, stage A -> sU, hoist py-regs =====
        {
            const float dy = positions[(b * NCH + c) * 2 + 0];
            const float dx = positions[(b * NCH + c) * 2 + 1];
            float sx, sy; sinpi_pair(dy, dx, sy, sx);
            Stot += sx * sy * (sQ[0] + sQ[1] + sQ[2] + sQ[3]);
        }

        bf16x8 Ah[2], Al[2];
        #pragma unroll
        for (int ks = 0; ks < 2; ++ks)
            #pragma unroll
            for (int d8 = 0; d8 < 8; ++d8) {
                const int m = 32 * ks + 8 * hh + d8;
                const float v  = raw[ks][d8][cc];
                const float sv = ((r + m) & 1) ? -v : v;
                const ushort h = f2bf(sv);
                const ushort l = f2bf(sv - bf2f(h));
                Ah[ks][d8] = (short)h;
                Al[ks][d8] = (short)l;
            }

        // stage A: per-tx accumulator (saves 28 VGPR), pack + write immediately
        #pragma unroll
        for (int tx = 0; tx < 8; ++tx) {
            f32x4 accA = zero;
            #pragma unroll
            for (int ks = 0; ks < 2; ++ks) {
                const int e0 = 16 * tx + nn + 96 - 32 * ks - 8 * hh;
                const int j0 = 223 - e0;
                const int a  = (-j0) & 7;
                const bf16x8 Bh = *(const bf16x8*)&sTab[0][0][a][j0 + a];
                const bf16x8 Bl = *(const bf16x8*)&sTab[0][1][a][j0 + a];
                accA = __builtin_amdgcn_mfma_f32_16x16x32_bf16(Ah[ks], Bh, accA, 0, 0, 0);
                accA = __builtin_amdgcn_mfma_f32_16x16x32_bf16(Ah[ks], Bl, accA, 0, 0, 0);
                accA = __builtin_amdgcn_mfma_f32_16x16x32_bf16(Al[ks], Bh, accA, 0, 0, 0);
            }
            const int x  = 16 * tx + nn;
            const int r0 = 16 * wv + 4 * hh;
            ushort h[4], l[4];
            #pragma unroll
            for (int g = 0; g < 4; ++g) {
                h[g] = f2bf(accA[g]);
                l[g] = f2bf(accA[g] - bf2f(h[g]));
            }
            const int idx = x * 64 + ((((r0 >> 3) ^ uSw(x))) << 3) + (r0 & 7);
            uint2v H, L;
            H[0] = (uint)h[0] | ((uint)h[1] << 16); H[1] = (uint)h[2] | ((uint)h[3] << 16);
            L[0] = (uint)l[0] | ((uint)l[1] << 16); L[1] = (uint)l[2] | ((uint)l[3] << 16);
            *(uint2v*)&sU[0][idx] = H;
            *(uint2v*)&sU[1][idx] = L;
        }

        // hoist stage-B py-operands into registers (frees sTab for next channel)
        #pragma unroll
        for (int ks = 0; ks < 2; ++ks) {
            {
                const int e0 = 16 * (2 * wv + 0) + nn + 96 - 32 * ks - 8 * hh;
                const int j0 = 223 - e0, a = (-j0) & 7;
                P0h[ks] = *(const bf16x8*)&sTab[1][0][a][j0 + a];
                P0l[ks] = *(const bf16x8*)&sTab[1][1][a][j0 + a];
            }
            {
                const int e0 = 16 * (2 * wv + 1) + nn + 96 - 32 * ks - 8 * hh;
                const int j0 = 223 - e0, a = (-j0) & 7;
                P1h[ks] = *(const bf16x8*)&sTab[1][0][a][j0 + a];
                P1l[ks] = *(const bf16x8*)&sTab[1][1][a][j0 + a];
            }
        }

        __syncthreads();   // sU(cc) ready; sTab now dead

        // ===== phase X(cc+1): [tables(c+1) + Q(c+1)] overlapped with stage-B(cc) =====
        if (cc + 1 < CG) {
            const int c1 = c + 1;
            const float dy = positions[(b * NCH + c1) * 2 + 0];
            const float dx = positions[(b * NCH + c1) * 2 + 1];
            float sx, sy; sinpi_pair(dy, dx, sy, sx);
            build_tables(sTab, dx, dy, sx, sy, tid);
            float qp = 0.f;
            #pragma unroll
            for (int ks = 0; ks < 2; ++ks)
                #pragma unroll
                for (int d8 = 0; d8 < 8; ++d8) {
                    const int m = 32 * ks + 8 * hh + d8;
                    const float v = raw[ks][d8][cc + 1];
                    qp += ((r + m) & 1) ? -v : v;
                }
            #pragma unroll
            for (int off = 32; off >= 1; off >>= 1) qp += __shfl_down(qp, off, 64);
            if (lane == 0) sQ[wv] = qp;
        }

        // stage B(cc): sU + reg-operands only (no sTab reads)
        #pragma unroll
        for (int ks = 0; ks < 2; ++ks) {
            const int rc = 4 * ks + hh;
            #pragma unroll
            for (int tx = 0; tx < 8; ++tx) {
                const int x = 16 * tx + nn;
                const int base = x * 64 + ((rc ^ uSw(x)) << 3);
                const bf16x8 Bu0 = *(const bf16x8*)&sU[0][base];
                const bf16x8 Bu1 = *(const bf16x8*)&sU[1][base];
                acc[0][tx] = __builtin_amdgcn_mfma_f32_16x16x32_bf16(P0h[ks], Bu0, acc[0][tx], 0, 0, 0);
                acc[1][tx] = __builtin_amdgcn_mfma_f32_16x16x32_bf16(P1h[ks], Bu0, acc[1][tx], 0, 0, 0);
                acc[0][tx] = __builtin_amdgcn_mfma_f32_16x16x32_bf16(P0h[ks], Bu1, acc[0][tx], 0, 0, 0);
                acc[1][tx] = __builtin_amdgcn_mfma_f32_16x16x32_bf16(P1h[ks], Bu1, acc[1][tx], 0, 0, 0);
                acc[0][tx] = __builtin_amdgcn_mfma_f32_16x16x32_bf16(P0l[ks], Bu0, acc[0][tx], 0, 0, 0);
                acc[1][tx] = __builtin_amdgcn_mfma_f32_16x16x32_bf16(P1l[ks], Bu0, acc[1][tx], 0, 0, 0);
            }
        }

        if (cc + 1 < CG) __syncthreads();  // sTab(c+1)/sQ(c+1) ready; sU reusable
    }

    // ---- epilogue: sign, rank-1 correction, scale ----
    const float inv = 1.f / 16384.f;
    if (USE_WS) {
        float* pb = dst + (size_t)(b * WPB + cg) * 16384;
        #pragma unroll
        for (int tyl = 0; tyl < 2; ++tyl)
            #pragma unroll
            for (int g = 0; g < 4; ++g) {
                const int y = 16 * (2 * wv + tyl) + 4 * hh + g;
                #pragma unroll
                for (int tx = 0; tx < 8; ++tx) {
                    const int x = 16 * tx + nn;
                    const float v = (acc[tyl][tx][g] - Stot) * inv;
                    pb[y * 128 + x] = ((x + y) & 1) ? -v : v;
                }
            }
    } else {
        float* ob = dst + (size_t)b * 16384;
        #pragma unroll
        for (int tyl = 0; tyl < 2; ++tyl)
            #pragma unroll
            for (int g = 0; g < 4; ++g) {
                const int y = 16 * (2 * wv + tyl) + 4 * hh + g;
                #pragma unroll
                for (int tx = 0; tx < 8; ++tx) {
                    const int x = 16 * tx + nn;
                    const float v = (acc[tyl][tx][g] - Stot) * inv;
                    atomicAdd(&ob[y * 128 + x], ((x + y) & 1) ? -v : v);
                }
            }
    }
}

__global__ __launch_bounds__(256)
void reduce_kernel(const float* __restrict__ ws, float* __restrict__ out, int B)
{
    const int t4 = blockIdx.x * 256 + threadIdx.x;
    if (t4 >= B * 4096) return;
    const int b = t4 >> 12, q = t4 & 4095;
    const f32x4* w4 = (const f32x4*)ws;
    f32x4 s = w4[(size_t)(b * WPB) * 4096 + q];
    #pragma unroll
    for (int g = 1; g < WPB; ++g) {
        f32x4 v = w4[(size_t)(b * WPB + g) * 4096 + q];
        s[0] += v[0]; s[1] += v[1]; s[2] += v[2]; s[3] += v[3];
    }
    ((f32x4*)out)[t4] = s;
}

extern "C" void kernel_launch(void* const* d_in, const int* in_sizes, int n_in,
                              void* d_out, int out_size, void* d_ws, size_t ws_size,
                              hipStream_t stream)
{
    const float* patches   = (const float*)d_in[0];
    const float* positions = (const float*)d_in[1];
    float* out = (float*)d_out;

    const int B = in_sizes[1] / (NCH * 2);                        // 128
    const size_t need = (size_t)B * WPB * 16384 * sizeof(float);  // 67 MB

    if (ws_size >= need) {
        reassemble_mfma<true><<<dim3(B * WPB), dim3(256), 0, stream>>>(
            patches, positions, (float*)d_ws, B);
        reduce_kernel<<<dim3((B * 4096 + 255) / 256), dim3(256), 0, stream>>>(
            (const float*)d_ws, out, B);
    } else {
        hipMemsetAsync(d_out, 0, (size_t)out_size * sizeof(float), stream);
        reassemble_mfma<false><<<dim3(B * WPB), dim3(256), 0, stream>>>(
            patches, positions, out, B);
    }
}